// Round 14
// baseline (117.560 us; speedup 1.0000x reference)
//
#include <hip/hip_runtime.h>
#include <hip/hip_bf16.h>
#include <math.h>

#define NCLS 20
#define KDIM 128
#define ALPHA 0.7f
#define BETA 1.5f

// ws float layout: [0,2560) class sums | [2560,+20) counts(int) | [2580,+20) intra
#define WS_SUMS 0
#define WS_CNT 2560
#define WS_INTRA 2580
#define WS_ZERO_N 2600

#define GRID 2048
#define SUMS_BLK 256
#define SUMS_GRID 1024   // 1024 * 256 = 262144 points exactly (tail handled anyway)

__global__ void k_init(float* ws) {
    const int tid = threadIdx.x;
    for (int i = tid; i < WS_ZERO_N; i += 256) ws[i] = 0.0f;
}

// ---- pass 1: block-local counting sort + class-grouped register gather-sum.
// Block owns a contiguous 256-point chunk (128KB window -> local reads).
// Sort 256 indices by class in LDS; each half-wave walks a 32-entry sorted
// segment: 8-deep batched 512B gathers, register accumulate, LDS-atomic
// flush on class change only. One 2560-wide global flush per block. ----
__global__ void __launch_bounds__(256) k_sums(const float4* __restrict__ emb4,
                                              const int* __restrict__ t,
                                              float* __restrict__ ws, int N) {
    __shared__ float lsum[NCLS * KDIM];
    __shared__ unsigned short sorted[SUMS_BLK];   // (class<<8) | local idx
    __shared__ int hist[NCLS], base[NCLS];
    const int tid = threadIdx.x;
    for (int i = tid; i < NCLS * KDIM; i += 256) lsum[i] = 0.0f;
    if (tid < NCLS) hist[tid] = 0;
    __syncthreads();

    const int chunk = blockIdx.x * SUMS_BLK;
    const int npts = min(SUMS_BLK, max(0, N - chunk));
    int c = -1, r = 0;
    if (tid < npts) {
        c = t[chunk + tid];
        r = atomicAdd(&hist[c], 1);
    }
    __syncthreads();
    if (tid < NCLS) {       // 20-wide exclusive prefix (tiny)
        int run = 0;
        for (int i = 0; i < NCLS; i++) run += (i < tid) ? hist[i] : 0;
        base[tid] = run;
        if (hist[tid]) atomicAdd((int*)&ws[WS_CNT] + tid, hist[tid]);
    }
    __syncthreads();
    if (c >= 0) sorted[base[c] + r] = (unsigned short)((c << 8) | tid);
    __syncthreads();

    const int s = tid & 31;
    const int off = (tid >> 5) * 32;              // segment 0..7
    const int m = min(32, npts - off);

    if (m > 0) {
        const unsigned short pk = sorted[off + min(s, m - 1)];
        const int myc = pk >> 8;
        const int myl = pk & 255;

        float4 acc = make_float4(0.f, 0.f, 0.f, 0.f);
        int ccur = -1;
#define FLUSHL()                                                   \
        {                                                          \
            float* a = &lsum[ccur * KDIM + 4 * s];                 \
            unsafeAtomicAdd(a + 0, acc.x);                         \
            unsafeAtomicAdd(a + 1, acc.y);                         \
            unsafeAtomicAdd(a + 2, acc.z);                         \
            unsafeAtomicAdd(a + 3, acc.w);                         \
        }
#define MERGE(C, V)                                                \
        {                                                          \
            if ((C) != ccur) {                                     \
                if (ccur >= 0) FLUSHL();                           \
                ccur = (C);                                        \
                acc = (V);                                         \
            } else {                                               \
                acc.x += (V).x; acc.y += (V).y;                    \
                acc.z += (V).z; acc.w += (V).w;                    \
            }                                                      \
        }
        if (m == 32) {
#pragma unroll
            for (int j0 = 0; j0 < 32; j0 += 8) {
                float4 v0, v1, v2, v3, v4, v5, v6, v7;
                int c0, c1, c2, c3, c4, c5, c6, c7;
#define G(jj) { const int li = __shfl(myl, j0 + jj, 32);               \
                c##jj = __shfl(myc, j0 + jj, 32);                      \
                v##jj = emb4[(size_t)(chunk + li) * 32 + s]; }
                G(0) G(1) G(2) G(3) G(4) G(5) G(6) G(7)
#undef G
                MERGE(c0, v0) MERGE(c1, v1) MERGE(c2, v2) MERGE(c3, v3)
                MERGE(c4, v4) MERGE(c5, v5) MERGE(c6, v6) MERGE(c7, v7)
            }
        } else {
            for (int j = 0; j < m; j++) {
                const int li = __shfl(myl, j, 32);
                const int cc = __shfl(myc, j, 32);
                const float4 v = emb4[(size_t)(chunk + li) * 32 + s];
                MERGE(cc, v)
            }
        }
        if (ccur >= 0) FLUSHL();
#undef MERGE
#undef FLUSHL
    }
    __syncthreads();

    for (int i = tid; i < NCLS * KDIM; i += 256)
        if (lsum[i] != 0.0f) unsafeAtomicAdd(&ws[WS_SUMS + i], lsum[i]);
}

// ---- pass 2 (R12-proven t-driven intra; counts as int) ----
__global__ void __launch_bounds__(256) k_intra(const float4* __restrict__ emb4,
                                               const int* __restrict__ t,
                                               const float* __restrict__ pts,
                                               float* __restrict__ ws, int N) {
    __shared__ float lmean[NCLS * KDIM];
    __shared__ float lintra[NCLS];
    const int tid = threadIdx.x;
    const int* gci = (const int*)&ws[WS_CNT];
    for (int i = tid; i < NCLS * KDIM; i += 256)
        lmean[i] = ws[WS_SUMS + i] / fmaxf((float)gci[i / KDIM], 1.0f);
    if (tid < NCLS) lintra[tid] = 0.0f;
    __syncthreads();

    const int s = tid & 31;
    const int pp = tid >> 5;
    const int stride = GRID * 8;
    for (int p = blockIdx.x * 8 + pp; p < N; p += 2 * stride) {
        const int p1 = p + stride;
        {
            const int c = t[p];
            const float4 v = emb4[(size_t)p * 32 + s];
            const float4 mm = *(const float4*)&lmean[c * KDIM + 4 * s];
            float dx = v.x - mm.x, dy = v.y - mm.y, dz = v.z - mm.z, dw = v.w - mm.w;
            float d2 = dx * dx + dy * dy + dz * dz + dw * dw;
            for (int off = 16; off >= 1; off >>= 1) d2 += __shfl_down(d2, off, 32);
            if (s == 0) {
                const float d = sqrtf(d2);
                const float px = pts[(size_t)p * 3 + 0];
                const float py = pts[(size_t)p * 3 + 1];
                const float pz = pts[(size_t)p * 3 + 2];
                const float rr = sqrtf(px * px + py * py + pz * pz);
                const float g = 1.0f / (1.0f + expf(-rr));
                const float h = fmaxf(d - ALPHA, 0.0f);
                unsafeAtomicAdd(&lintra[c], g * h * h);
            }
        }
        if (p1 < N) {
            const int c = t[p1];
            const float4 v = emb4[(size_t)p1 * 32 + s];
            const float4 mm = *(const float4*)&lmean[c * KDIM + 4 * s];
            float dx = v.x - mm.x, dy = v.y - mm.y, dz = v.z - mm.z, dw = v.w - mm.w;
            float d2 = dx * dx + dy * dy + dz * dz + dw * dw;
            for (int off = 16; off >= 1; off >>= 1) d2 += __shfl_down(d2, off, 32);
            if (s == 0) {
                const float d = sqrtf(d2);
                const float px = pts[(size_t)p1 * 3 + 0];
                const float py = pts[(size_t)p1 * 3 + 1];
                const float pz = pts[(size_t)p1 * 3 + 2];
                const float rr = sqrtf(px * px + py * py + pz * pz);
                const float g = 1.0f / (1.0f + expf(-rr));
                const float h = fmaxf(d - ALPHA, 0.0f);
                unsafeAtomicAdd(&lintra[c], g * h * h);
            }
        }
    }
    __syncthreads();
    if (tid < NCLS) unsafeAtomicAdd(&ws[WS_INTRA + tid], lintra[tid]);
}

// ---- final (int counts) ----
__global__ void __launch_bounds__(256) k_final(const float* __restrict__ ws,
                                               float* __restrict__ out) {
    __shared__ float lmean[NCLS * KDIM];
    __shared__ float red[256];
    const int tid = threadIdx.x;
    const int* gci = (const int*)&ws[WS_CNT];
    for (int i = tid; i < NCLS * KDIM; i += 256)
        lmean[i] = ws[WS_SUMS + i] / fmaxf((float)gci[i / KDIM], 1.0f);
    __syncthreads();

    float acc = 0.0f;
    for (int idx = tid; idx < 361; idx += 256) {
        const int i = idx / 19 + 1;
        const int j = idx % 19 + 1;
        if (i != j) {
            float sq = 0.0f;
            const float* mi = lmean + i * KDIM;
            const float* mj = lmean + j * KDIM;
            for (int k = 0; k < KDIM; k++) {
                const float df = mi[k] - mj[k];
                sq += df * df;
            }
            const float dist = sqrtf(sq);
            const float h = fmaxf(BETA - dist, 0.0f);
            acc += h * h;
        }
    }
    red[tid] = acc;
    __syncthreads();
    for (int st = 128; st >= 1; st >>= 1) {
        if (tid < st) red[tid] += red[tid + st];
        __syncthreads();
    }
    if (tid == 0) {
        float intra = 0.0f;
        for (int c = 1; c < NCLS; c++)
            intra += ws[WS_INTRA + c] / fmaxf((float)gci[c], 1.0f);
        out[0] = intra / (float)NCLS + red[0] / (float)(NCLS * (NCLS - 1));
    }
}

extern "C" void kernel_launch(void* const* d_in, const int* in_sizes, int n_in,
                              void* d_out, int out_size, void* d_ws, size_t ws_size,
                              hipStream_t stream) {
    const float* pts = (const float*)d_in[0];
    const int* t = (const int*)d_in[1];
    const float4* emb4 = (const float4*)d_in[2];
    float* out = (float*)d_out;
    float* ws = (float*)d_ws;
    const int N = in_sizes[1];
    const int nblk = (N + SUMS_BLK - 1) / SUMS_BLK;

    k_init<<<1, 256, 0, stream>>>(ws);
    k_sums<<<nblk, SUMS_BLK, 0, stream>>>(emb4, t, ws, N);
    k_intra<<<GRID, 256, 0, stream>>>(emb4, t, pts, ws, N);
    k_final<<<1, 256, 0, stream>>>(ws, out);
}